// Round 1
// baseline (261.998 us; speedup 1.0000x reference)
//
#include <hip/hip_runtime.h>
#include <hip/hip_bf16.h>
#include <stdint.h>

// Problem constants (from reference)
#define B_N     2048
#define E_N     32
#define IN_N    2048
#define OUT_N   1024
#define TOPK    4

// GEMM tiling
#define BM      64
#define BN      256
#define BK      32
#define NT      (OUT_N / BN)        // 4 n-tiles
#define THREADS 256                 // 4 waves
#define MAX_SLOTS 160               // sum ceil(count_e/BM) <= 8192/64 + 32
#define GRID_GEMM (MAX_SLOTS * NT)  // 640, divisible by 8 (XCD swizzle bijective)

// ws layout (int words)
#define WS_COUNTS 0     // [32]
#define WS_NSLOTS 32    // [1]
#define WS_DESC   64    // [MAX_SLOTS]  packed (e<<6)|mt
#define WS_LISTS  256   // [E_N][B_N]   packed (b<<2)|k

typedef float  f32x4  __attribute__((ext_vector_type(4)));
typedef __bf16 bf16x8 __attribute__((ext_vector_type(8)));

union Pack8 { bf16x8 v; uint4 u; };

__device__ __forceinline__ uint4 pack8(f32x4 lo, f32x4 hi) {
  Pack8 p;
#pragma unroll
  for (int j = 0; j < 4; ++j) { p.v[j] = (__bf16)lo[j]; p.v[j + 4] = (__bf16)hi[j]; }
  return p.u;
}
__device__ __forceinline__ bf16x8 as_frag(uint4 u) { Pack8 p; p.u = u; return p.v; }

// ---------------- kernel 0: zero counters ----------------
__global__ void k_zero(int* __restrict__ ws) {
  if (threadIdx.x < 64) ws[threadIdx.x] = 0;
}

// ---------------- kernel 1: top-4-smallest + bucket ----------------
__global__ void k_topk(const float* __restrict__ act, int* __restrict__ ws) {
  int b = blockIdx.x * blockDim.x + threadIdx.x;
  if (b >= B_N) return;
  float v[E_N];
  const float* a = act + (size_t)b * E_N;
#pragma unroll
  for (int e = 0; e < E_N; ++e) v[e] = a[e];
  unsigned chosen = 0;
#pragma unroll
  for (int k = 0; k < TOPK; ++k) {
    float mv = 3.4e38f; int mi = 0;
#pragma unroll
    for (int e = 0; e < E_N; ++e) {
      bool sel = (((chosen >> e) & 1u) == 0u) && (v[e] < mv);  // strict <: stable (first index)
      mv = sel ? v[e] : mv;
      mi = sel ? e : mi;
    }
    chosen |= (1u << mi);
    int pos = atomicAdd(&ws[WS_COUNTS + mi], 1);
    ws[WS_LISTS + mi * B_N + pos] = (b << 2) | k;
  }
}

// ---------------- kernel 2: build tile worklist ----------------
__global__ void k_tiles(int* __restrict__ ws) {
  int e = threadIdx.x;  // launched with 64 (one wave)
  int c = (e < E_N) ? ws[WS_COUNTS + e] : 0;
  int t = (c + BM - 1) / BM;
  int off = 0, tot = 0;
  for (int j = 0; j < E_N; ++j) {
    int tj = __shfl(t, j, 64);
    if (j < e) off += tj;
    tot += tj;
  }
  if (e < E_N) {
    for (int i = 0; i < t; ++i) ws[WS_DESC + off + i] = (e << 6) | i;
  }
  if (e == 0) ws[WS_NSLOTS] = tot;
}

// ---------------- kernel 3: grouped GEMM (bf16 MFMA) ----------------
// block tile: BM=64 rows (gathered (b,k) pairs of one expert) x BN=256 cols
// 4 waves, each wave owns 64x64 via 4x4 fragments of mfma_f32_16x16x32_bf16
__global__ __launch_bounds__(THREADS, 2)
void k_gemm(const float* __restrict__ feat, const float* __restrict__ Wm,
            const float* __restrict__ bias, const int* __restrict__ ws,
            float* __restrict__ out) {
  // XCD-chunked swizzle: consecutive logical blocks -> same XCD (L2 reuse of W[e])
  int p = blockIdx.x;
  int L = (p & 7) * (GRID_GEMM / 8) + (p >> 3);
  int slot = L >> 2;       // logical order: slot-major, nt inner
  int nt   = L & 3;
  if (slot >= ws[WS_NSLOTS]) return;
  int desc = ws[WS_DESC + slot];
  int e = desc >> 6, mt = desc & 63;
  int count = ws[WS_COUNTS + e];
  int m0 = mt * BM;

  __shared__ char lds[BM * BK * 2 + BN * BK * 2];  // A 4KB + W 16KB (bf16)
  uint4* Alds = (uint4*)lds;                       // 256 slots of 16B
  uint4* Wlds = (uint4*)(lds + BM * BK * 2);       // 1024 slots of 16B
  __shared__ int gids[BM];

  int tid  = threadIdx.x;
  int lane = tid & 63;
  int wv   = tid >> 6;

  // --- A staging assignment: 4 threads per row, 8 floats each ---
  int arow = tid >> 2, aseg = tid & 3;
  int gid = -1;
  if (m0 + arow < count) gid = ws[WS_LISTS + e * B_N + m0 + arow];
  if (aseg == 0) gids[arow] = gid;
  const float* aptr = feat + (size_t)(gid >> 2) * IN_N + aseg * 8;  // valid only if gid>=0
  int a_wi = (arow * 64 + ((aseg ^ ((arow >> 1) & 3)) * 16)) >> 4;  // swizzled uint4 idx

  // --- W staging assignment: 1 thread per row (32 floats = 128B) ---
  int wrow = tid;
  const float* wptr = Wm + ((size_t)e * OUT_N + (size_t)(nt * BN + wrow)) * IN_N;
  int wswz = (wrow >> 1) & 3;

  // --- fragment read addresses (uint4 indices, swizzled) ---
  int aidx[4], bidx[4];
#pragma unroll
  for (int mi = 0; mi < 4; ++mi) {
    int r = mi * 16 + (lane & 15);
    aidx[mi] = (r * 64 + (((lane >> 4) ^ ((r >> 1) & 3)) * 16)) >> 4;
  }
#pragma unroll
  for (int ni = 0; ni < 4; ++ni) {
    int r = wv * 64 + ni * 16 + (lane & 15);
    bidx[ni] = (r * 64 + (((lane >> 4) ^ ((r >> 1) & 3)) * 16)) >> 4;
  }

  f32x4 acc[4][4] = {};  // [mi][ni]

#pragma unroll 1
  for (int kt = 0; kt < IN_N / BK; ++kt) {
    int k0 = kt * BK;
    // global loads (issue before barrier: overlap previous tile's compute)
    f32x4 a0 = {0.f, 0.f, 0.f, 0.f}, a1 = {0.f, 0.f, 0.f, 0.f};
    if (gid >= 0) {
      a0 = *(const f32x4*)(aptr + k0);
      a1 = *(const f32x4*)(aptr + k0 + 4);
    }
    f32x4 w[8];
#pragma unroll
    for (int i = 0; i < 8; ++i) w[i] = *(const f32x4*)(wptr + k0 + i * 4);

    __syncthreads();  // previous compute done, LDS reusable
    Alds[a_wi] = pack8(a0, a1);
#pragma unroll
    for (int s = 0; s < 4; ++s) {
      Wlds[(wrow * 64 + ((s ^ wswz) * 16)) >> 4] = pack8(w[2 * s], w[2 * s + 1]);
    }
    __syncthreads();  // tile staged

    bf16x8 af[4], bfr[4];
#pragma unroll
    for (int mi = 0; mi < 4; ++mi) af[mi] = as_frag(Alds[aidx[mi]]);
#pragma unroll
    for (int ni = 0; ni < 4; ++ni) bfr[ni] = as_frag(Wlds[bidx[ni]]);
#pragma unroll
    for (int mi = 0; mi < 4; ++mi)
#pragma unroll
      for (int ni = 0; ni < 4; ++ni)
        acc[mi][ni] = __builtin_amdgcn_mfma_f32_16x16x32_bf16(af[mi], bfr[ni], acc[mi][ni], 0, 0, 0);
  }

  // --- epilogue: D row = (lane>>4)*4 + j, col = lane&15  [m89 verified layout] ---
  int grr[16];
#pragma unroll
  for (int mi = 0; mi < 4; ++mi)
#pragma unroll
    for (int j = 0; j < 4; ++j) grr[mi * 4 + j] = gids[mi * 16 + (lane >> 4) * 4 + j];

#pragma unroll
  for (int ni = 0; ni < 4; ++ni) {
    int col = nt * BN + wv * 64 + ni * 16 + (lane & 15);
    float bs = bias[e * OUT_N + col];
#pragma unroll
    for (int mi = 0; mi < 4; ++mi) {
#pragma unroll
      for (int j = 0; j < 4; ++j) {
        int g = grr[mi * 4 + j];
        if (g >= 0) out[(size_t)g * OUT_N + col] = acc[mi][ni][j] + bs;
      }
    }
  }
}

extern "C" void kernel_launch(void* const* d_in, const int* in_sizes, int n_in,
                              void* d_out, int out_size, void* d_ws, size_t ws_size,
                              hipStream_t stream) {
  const float* feat = (const float*)d_in[0];   // [B, IN]
  const float* Wm   = (const float*)d_in[1];   // [E, OUT, IN]
  const float* bias = (const float*)d_in[2];   // [E, OUT]
  const float* act  = (const float*)d_in[3];   // [B, E]
  // d_in[4] = top_k (device scalar) -- compile-time TOPK=4
  int*   ws  = (int*)d_ws;
  float* out = (float*)d_out;

  hipLaunchKernelGGL(k_zero,  dim3(1),          dim3(64),      0, stream, ws);
  hipLaunchKernelGGL(k_topk,  dim3(B_N / 256),  dim3(256),     0, stream, act, ws);
  hipLaunchKernelGGL(k_tiles, dim3(1),          dim3(64),      0, stream, ws);
  hipLaunchKernelGGL(k_gemm,  dim3(GRID_GEMM),  dim3(THREADS), 0, stream,
                     feat, Wm, bias, ws, out);
}